// Round 16
// baseline (139.135 us; speedup 1.0000x reference)
//
#include <hip/hip_runtime.h>

// ---------------- problem constants ----------------
#define DM    1024          // d_model
#define NEXP  8             // experts
#define BTOK  8192          // tokens
#define KTOP  2             // routes per token
#define NASSIGN (BTOK*KTOP) // 16384
#define CAPC  1280          // capacity (5 * 256 -> tile-aligned)
#define MROWS (NEXP*CAPC)   // 10240 expert rows

// GEMM geometry: 256M x 128N tile, BK=32, 8 waves (4Mx2N), per-wave 64x64
#define NTILES   (DM/128)      // 8
#define SLOTS_E  (5*NTILES)    // 40 expert slots per XCD (5 Mtiles x 8 N)
#define SLOTS_F  (32*NTILES/8) // 32 fb slots per XCD
#define SLOTS    (SLOTS_E+SLOTS_F)    // 72
#define GRID_L   (8*SLOTS)            // 576

typedef unsigned short ushort_t;
typedef __attribute__((ext_vector_type(8))) __bf16 bf16x8;
typedef __attribute__((ext_vector_type(4))) float  f32x4;

__device__ __forceinline__ ushort_t f2b(float f) {  // f32 -> bf16 RNE
  union { float f; unsigned u; } a; a.f = f;
  unsigned u = a.u;
  return (ushort_t)((u + 0x7FFFu + ((u >> 16) & 1u)) >> 16);
}

#define GLOAD_LDS(g, l) __builtin_amdgcn_global_load_lds( \
    (const __attribute__((address_space(1))) void*)(g),   \
    (__attribute__((address_space(3))) void*)(l), 16, 0, 0)

// -------- merged: routing (b 0..7) + W cvt (b 8..4615) + x cvt (b 4616..6663)
//          + xb zero-row (b 6664) ----------
// r16: x is converted to bf16 ONCE (xb, BTOK+1 rows; row BTOK = zeros); the
// GEMM gathers A rows directly from xb via per-lane global_load_lds source
// addresses (m173) -- the xg/xf gather kernels are eliminated.  Routing
// blocks also init fbidx[i]=BTOK and fill gidx padding with BTOK (-> zero row).
__global__ void route_cvt_kernel(const int* __restrict__ routes, const int* __restrict__ capp,
                                 int* __restrict__ gidx, int* __restrict__ slot,
                                 int* __restrict__ nfb, int* __restrict__ fbidx,
                                 const float* __restrict__ W1, const float* __restrict__ W2,
                                 const float* __restrict__ Wf1, const float* __restrict__ Wf2,
                                 ushort_t* __restrict__ o1, ushort_t* __restrict__ o2,
                                 ushort_t* __restrict__ of1, ushort_t* __restrict__ of2,
                                 const float* __restrict__ x, ushort_t* __restrict__ xb) {
  const int b = blockIdx.x, t = threadIdx.x;
  if (b >= 8) {
    int c = b - 8;
    if (c < 6656) {                      // f32 -> bf16 cvt (W1,W2,Wf1,Wf2,x)
      const float* s; ushort_t* d; int idx;
      if (c < 2048)      { s = W1;  d = o1;  idx = c; }
      else if (c < 4096) { s = W2;  d = o2;  idx = c - 2048; }
      else if (c < 4352) { s = Wf1; d = of1; idx = c - 4096; }
      else if (c < 4608) { s = Wf2; d = of2; idx = c - 4352; }
      else               { s = x;   d = xb;  idx = c - 4608; }
      int i = idx * 1024 + t;
      float4 v = ((const float4*)s)[i];
      ushort4 o; o.x = f2b(v.x); o.y = f2b(v.y); o.z = f2b(v.z); o.w = f2b(v.w);
      ((ushort4*)d)[i] = o;
    } else if (t < 256) {                // zero row BTOK of xb
      ushort4 z = {0, 0, 0, 0};
      ((ushort4*)(xb + (size_t)BTOK * DM))[t] = z;
    }
    return;
  }
  // ---- routing: exact sequential capacity semantics (block e = expert) ----
  const int e = b;
  const int lane = t & 63, w = t >> 6;
  int cap = *capp; if (cap > CAPC) cap = CAPC;
  if (e == 0 && t == 0) *nfb = 0;
  fbidx[e * 1024 + t] = BTOK;            // init fb list to zero-row (safe: fblist runs later)
  __shared__ int wtot[16];
  int base = 0;
  for (int i0 = 0; i0 < NASSIGN; i0 += 1024) {
    int i = i0 + t;
    int r = routes[i];
    bool mine = (r == e);
    unsigned long long mask = __ballot(mine);
    int pre = __popcll(mask & ((1ull << lane) - 1ull));
    if (lane == 0) wtot[w] = __popcll(mask);
    __syncthreads();
    int tot = 0;
#pragma unroll
    for (int j = 0; j < 16; ++j) { int c = wtot[j]; if (j < w) pre += c; tot += c; }
    if (e == 0 && (unsigned)r >= NEXP) slot[i] = -1;  // defensive (never triggers)
    if (mine) {
      int pos = base + pre;
      if (pos < cap) { gidx[e * CAPC + pos] = i >> 1; slot[i] = e * CAPC + pos; }
      else slot[i] = -1;
    }
    base += tot;
    __syncthreads();
  }
  int cnt = base < cap ? base : cap;
  for (int pos = cnt + t; pos < CAPC; pos += 1024)
    gidx[e * CAPC + pos] = BTOK;         // padding -> zero row, suppressed in epilogue
}

// ---------------- fb list + per-token 1/u ----------------
__global__ void fblist_kernel(const int* __restrict__ slot, int* __restrict__ fbidx,
                              int* __restrict__ nfb, float* __restrict__ invu) {
  int tok = blockIdx.x * 256 + threadIdx.x;
  if (tok >= BTOK) return;
  int u = (slot[2 * tok] >= 0) + (slot[2 * tok + 1] >= 0);
  invu[tok] = u ? 1.0f / (float)u : 0.0f;
  if (u == 0) { int p = atomicAdd(nfb, 1); fbidx[p] = tok; }
}

// ---------------- fused layer GEMM: expert part + fallback part ----------------
// C[m,n] = A[m,k]*W[n,k] + bias[n].  256x128 tile, BK=32, 8 waves (4Mx2N),
// per-wave 64x64 (acc in AGPRs, VGPR 64 -> 2 blocks/CU, 16 waves/CU -- r15).
// Simple 2-phase dbuf, ONE __syncthreads per K-step (proven r9/r12/r15 loop).
// LAYER=1: A gathered per-lane from xb (expert: gidx, fb: fbidx; padding ->
//   zero row), RELU, bf16 C via LDS repack (H / Hf).
// LAYER=2: A dense from H/Hf; expert epilogue atomicAdds (acc+b2)*invu[tok]
//   into out (deterministic: <=2 commutative f32 adds per element onto
//   memset-0); fb epilogue scatters rows < nfb.  Y and combine eliminated.
// XCD expert affinity kept; LDS XOR swizzle kept.
template <int LAYER>
__global__ __launch_bounds__(512, 4) void layer_kernel(
    const ushort_t* __restrict__ Ae, const ushort_t* __restrict__ We,
    const float* __restrict__ be, ushort_t* __restrict__ Ce,
    const ushort_t* __restrict__ Af, const ushort_t* __restrict__ Wf,
    const float* __restrict__ bfp, ushort_t* __restrict__ Cf,
    float* __restrict__ outF, const int* __restrict__ gidxp,
    const int* __restrict__ fbidxp, const float* __restrict__ invu,
    const int* __restrict__ nfbp) {
  const int b = blockIdx.x;
  const int xcd = b & 7, s = b >> 3;
  const ushort_t* A; const ushort_t* W; const float* bias; ushort_t* C;
  int mgrp, ntile; bool isfb;
  if (s < SLOTS_E) {
    const int e = xcd;                       // expert = XCD (L2 affinity)
    mgrp = e * 5 + (s >> 3); ntile = s & 7;  // N-fastest
    A = Ae; W = We + (size_t)e * DM * DM; bias = be + e * DM; C = Ce; isfb = false;
  } else {
    int fl = (s - SLOTS_E) * 8 + xcd;        // 0..255 spread over XCDs
    mgrp = fl >> 3; ntile = fl & 7;
    if (mgrp * 256 >= *nfbp) return;
    A = Af; W = Wf; bias = bfp; C = Cf; isfb = true;
  }
  const int tid = threadIdx.x, lane = tid & 63, w = tid >> 6;  // w 0..7
  const int wr = w >> 1, wc = w & 1;        // 4Mx2N wave grid
  __shared__ ushort_t smem[24576];          // 48KB: A dbuf 2x16KB, B dbuf 2x8KB
  const size_t Wbase = (size_t)ntile * 128 * DM;
  f32x4 acc[4][4] = {};

  // staging: A = 16 segs of 16 rows x 32k (1KB), wave w stages segs 2w,2w+1;
  // B = 8 segs, wave w stages seg w.  3 global_load_lds per thread per K-step.
  const int sub  = lane >> 2;                     // row within 16-row seg
  const int slt  = lane & 3;                      // 16B k-slot
  const int gcol = (slt ^ ((sub >> 1) & 3)) * 8;  // inverse-swizzled source k-off
  const int ra0 = (w * 2)     * 16 + sub;
  const int ra1 = (w * 2 + 1) * 16 + sub;
  const int rbw = w * 16 + sub;

  // per-lane A source rows (constant over K): LAYER1 gathers token rows
  size_t sA0, sA1;
  if (LAYER == 1) {
    int row0 = mgrp * 256 + ra0, row1 = mgrp * 256 + ra1;
    int t0 = isfb ? fbidxp[row0] : gidxp[row0];
    int t1 = isfb ? fbidxp[row1] : gidxp[row1];
    sA0 = (size_t)t0 * DM; sA1 = (size_t)t1 * DM;
  } else {
    sA0 = (size_t)(mgrp * 256 + ra0) * DM;
    sA1 = (size_t)(mgrp * 256 + ra1) * DM;
  }

  // LDS elems: A buf0 @0, A buf1 @8192, B buf0 @16384, B buf1 @20480
#define STAGE(T, BUF) do { int kt_ = (T) * 32;                                        \
    GLOAD_LDS(A + sA0 + kt_ + gcol, smem + (BUF)*8192 + (w*2)  *512);                 \
    GLOAD_LDS(A + sA1 + kt_ + gcol, smem + (BUF)*8192 + (w*2+1)*512);                 \
    GLOAD_LDS(W + Wbase + (size_t)rbw * DM + kt_ + gcol, smem + 16384 + (BUF)*4096 + w*512); \
  } while (0)

  const int fr    = lane & 15, g = lane >> 4;
  const int rslot = (g ^ ((fr >> 1) & 3)) * 8;    // swizzled read k-off

  STAGE(0, 0);
  for (int t = 0; t < 32; ++t) {
    __syncthreads();                    // vmcnt(0) drain: tile t landed; and
                                        // buf[p^1]'s readers (iter t-1) passed
    if (t + 1 < 32) STAGE(t + 1, (t + 1) & 1);
    const ushort_t* bA = smem + (t & 1) * 8192;
    const ushort_t* bB = smem + 16384 + (t & 1) * 4096;
    bf16x8 av[4], bv[4];
#pragma unroll
    for (int m = 0; m < 4; ++m)
      av[m] = *(const bf16x8*)&bA[(wr * 64 + m * 16 + fr) * 32 + rslot];
#pragma unroll
    for (int n = 0; n < 4; ++n)
      bv[n] = *(const bf16x8*)&bB[(wc * 64 + n * 16 + fr) * 32 + rslot];
#pragma unroll
    for (int m = 0; m < 4; ++m)
#pragma unroll
      for (int n = 0; n < 4; ++n)
        acc[m][n] = __builtin_amdgcn_mfma_f32_16x16x32_bf16(av[m], bv[n], acc[m][n], 0, 0, 0);
  }
#undef STAGE

  // epilogue.  C/D layout col=lane&15, row=(lane>>4)*4+reg  [m89-verified]
  if (LAYER == 2) {
    if (isfb) {                         // fb: scatter rows < nfb into out
      int nfbv = *nfbp;
#pragma unroll
      for (int n = 0; n < 4; ++n) {
        int col = ntile * 128 + wc * 64 + n * 16 + fr;
        float bb = bias[col];
#pragma unroll
        for (int m = 0; m < 4; ++m) {
          int row0 = mgrp * 256 + wr * 64 + m * 16 + g * 4;
#pragma unroll
          for (int r = 0; r < 4; ++r) {
            int row = row0 + r;
            if (row < nfbv) outF[(size_t)fbidxp[row] * DM + col] = acc[m][n][r] + bb;
          }
        }
      }
    } else {                            // expert: atomic combine into out
#pragma unroll
      for (int n = 0; n < 4; ++n) {
        int col = ntile * 128 + wc * 64 + n * 16 + fr;
        float bb = bias[col];
#pragma unroll
        for (int m = 0; m < 4; ++m) {
          int row0 = mgrp * 256 + wr * 64 + m * 16 + g * 4;
#pragma unroll
          for (int r = 0; r < 4; ++r) {
            int tok = gidxp[row0 + r];
            if (tok != BTOK)
              atomicAdd(outF + (size_t)tok * DM + col, (acc[m][n][r] + bb) * invu[tok]);
          }
        }
      }
    }
  } else {                              // LAYER 1: bf16 C via LDS repack, 2 halves
    ushort_t* Cb = C + (size_t)mgrp * 256 * DM + ntile * 128;
#pragma unroll
    for (int h = 0; h < 2; ++h) {
      __syncthreads();                  // staging reads (h=0) / prior copy (h=1) done
      if ((wr >> 1) == h) {             // waves wr={2h,2h+1} own these 128 rows
#pragma unroll
        for (int n = 0; n < 4; ++n) {
          int col = wc * 64 + n * 16 + fr;
          float bb = bias[ntile * 128 + col];
#pragma unroll
          for (int m = 0; m < 4; ++m) {
            int lrow0 = (wr & 1) * 64 + m * 16 + g * 4;
#pragma unroll
            for (int r = 0; r < 4; ++r) {
              float v = acc[m][n][r] + bb;
              v = v > 0.0f ? v : 0.0f;  // LAYER1 always ReLU
              smem[(lrow0 + r) * 128 + col] = f2b(v);
            }
          }
        }
      }
      __syncthreads();
      // copy 128x128 bf16 half-tile: 2048 chunks of 16B, 512 thr x 4
#pragma unroll
      for (int q = 0; q < 4; ++q) {
        int chunk = q * 512 + tid;      // 0..2047
        int row = chunk >> 4, co = (chunk & 15) * 8;
        bf16x8 v = *(const bf16x8*)&smem[row * 128 + co];
        *(bf16x8*)(Cb + (size_t)(h * 128 + row) * DM + co) = v;
      }
    }
  }
}

// ---------------- launch ----------------
extern "C" void kernel_launch(void* const* d_in, const int* in_sizes, int n_in,
                              void* d_out, int out_size, void* d_ws, size_t ws_size,
                              hipStream_t stream) {
  const float* x   = (const float*)d_in[0];
  const float* W1  = (const float*)d_in[1];
  const float* b1  = (const float*)d_in[2];
  const float* W2  = (const float*)d_in[3];
  const float* b2  = (const float*)d_in[4];
  const float* Wf1 = (const float*)d_in[5];
  const float* bf1 = (const float*)d_in[6];
  const float* Wf2 = (const float*)d_in[7];
  const float* bf2 = (const float*)d_in[8];
  const int* routes = (const int*)d_in[9];
  const int* capp   = (const int*)d_in[10];
  float* out = (float*)d_out;

  char* ws = (char*)d_ws;
  size_t off = 0;
  auto alloc = [&](size_t bytes) -> void* {
    void* p = ws + off; off += (bytes + 255) & ~255ull; return p;
  };
  ushort_t* W1b  = (ushort_t*)alloc((size_t)NEXP * DM * DM * 2);
  ushort_t* W2b  = (ushort_t*)alloc((size_t)NEXP * DM * DM * 2);
  ushort_t* Wf1b = (ushort_t*)alloc((size_t)DM * DM * 2);
  ushort_t* Wf2b = (ushort_t*)alloc((size_t)DM * DM * 2);
  ushort_t* xb   = (ushort_t*)alloc((size_t)(BTOK + 1) * DM * 2);
  ushort_t* H    = (ushort_t*)alloc((size_t)MROWS * DM * 2);
  ushort_t* Hf   = (ushort_t*)alloc((size_t)BTOK * DM * 2);
  int*   gidx  = (int*)alloc(MROWS * 4);
  int*   slot  = (int*)alloc(NASSIGN * 4);
  int*   fbidx = (int*)alloc(BTOK * 4);
  float* invu  = (float*)alloc(BTOK * 4);
  int*   nfb   = (int*)alloc(4);

  hipMemsetAsync(out, 0, (size_t)out_size * 4, stream);
  route_cvt_kernel<<<6665, 1024, 0, stream>>>(routes, capp, gidx, slot, nfb, fbidx,
                                              W1, W2, Wf1, Wf2, W1b, W2b, Wf1b, Wf2b,
                                              x, xb);
  fblist_kernel<<<BTOK / 256, 256, 0, stream>>>(slot, fbidx, nfb, invu);
  layer_kernel<1><<<GRID_L, 512, 0, stream>>>(xb, W1b, b1, H, xb, Wf1b, bf1, Hf,
                                              nullptr, gidx, fbidx, invu, nfb);
  layer_kernel<2><<<GRID_L, 512, 0, stream>>>(H, W2b, b2, nullptr, Hf, Wf2b, bf2, nullptr,
                                              out, gidx, fbidx, invu, nfb);
}